// Round 5
// baseline (376.554 us; speedup 1.0000x reference)
//
#include <hip/hip_runtime.h>

// ---------------------------------------------------------------------------
// MoE block: x[2,2048,1024] fp32, 8 experts, top-2 routing, f=2048, LN output.
// v10: pipeline restructure. Transpose access-pattern work is DONE (4 variants
//      all pinned 63-72us at ~2.8 TB/s effective; mixed fp32-read/bf16-write
//      path limit). Instead: overlap + dispatch-count reduction.
//      - gate+scatter fused, slots via global atomicAdd (capacity 1152/expert,
//        counts 1024+-30 => ~8 sigma); scan/scatter kernels deleted.
//      - W1 transpose fused into prep_kernel (hides gate under its BW).
//      - W2 transpose fused into gemm1 grid as z-slices 9..24 (gemm1 is
//        compute-bound at 15% HBM -> transpose rides free bandwidth).
//      - GEMM inner loop untouched (v3 proven structure, k-chunked B).
//      7 kernels -> 4 (+1 tiny memset).
// ---------------------------------------------------------------------------

typedef unsigned short ushort_t;
typedef short short8 __attribute__((ext_vector_type(8)));
typedef float f32x4 __attribute__((ext_vector_type(4)));

#define T_TOKENS 4096
#define DMODEL 1024
#define FFN 2048
#define NEXP 8
#define ECAP 1152          // fixed slot capacity per expert (8*1152 = 9216)
#define MAXSLOTS 9216
#define MT1 9              // ceil(ECAP/128)

__device__ __forceinline__ ushort_t f2bf(float f) {
    unsigned u = __float_as_uint(f);
    return (ushort_t)((u + 0x7fffu + ((u >> 16) & 1u)) >> 16);
}
__device__ __forceinline__ float bflo(unsigned packed) {
    return __uint_as_float(packed << 16);
}
__device__ __forceinline__ float bfhi(unsigned packed) {
    return __uint_as_float(packed & 0xffff0000u);
}

__device__ __forceinline__ void gload_lds16(const void* g, void* l) {
    __builtin_amdgcn_global_load_lds(
        (const __attribute__((address_space(1))) unsigned int*)g,
        (__attribute__((address_space(3))) unsigned int*)l,
        16, 0, 0);
}

// ---------------------------------------------------------------------------
// k-chunked transpose block: Wsrc[K,N] fp32 -> Wdst[K/32][N][32] bf16,
// one (kc, 256-wide n-strip). Contiguous reads (1KB/row-visit) and one
// contiguous 16KB write range (complete 64B sectors per store instr).
// smem: 32*260 ushorts (16640 B).
__device__ __forceinline__ void wt_block(
    const float* __restrict__ Wsrc, ushort_t* __restrict__ Wdst,
    int e, int kc, int ns, int N, ushort_t* sm)
{
    const float* s = Wsrc + (size_t)e * DMODEL * FFN;
    ushort_t* d = Wdst + (size_t)e * DMODEL * FFN;
    const int k0 = kc * 32, n0 = ns * 256;
    const int tid = threadIdx.x;
    #pragma unroll
    for (int i = 0; i < 8; i++) {
        int k = i * 4 + (tid >> 6);        // 0..31
        int n = (tid & 63) * 4;            // 0..252
        float4 v = *(const float4*)&s[(size_t)(k0 + k) * N + n0 + n];
        uint2 pk;
        pk.x = (unsigned)f2bf(v.x) | ((unsigned)f2bf(v.y) << 16);
        pk.y = (unsigned)f2bf(v.z) | ((unsigned)f2bf(v.w) << 16);
        *(uint2*)&sm[k * 260 + n] = pk;
    }
    __syncthreads();
    const int sub = tid & 3;
    const int nl0 = tid >> 2;              // 0..63
    #pragma unroll
    for (int it = 0; it < 4; it++) {
        int n = nl0 + it * 64;             // 0..255
        uint4 o;
        o.x = (unsigned)sm[(sub * 8 + 0) * 260 + n] | ((unsigned)sm[(sub * 8 + 1) * 260 + n] << 16);
        o.y = (unsigned)sm[(sub * 8 + 2) * 260 + n] | ((unsigned)sm[(sub * 8 + 3) * 260 + n] << 16);
        o.z = (unsigned)sm[(sub * 8 + 4) * 260 + n] | ((unsigned)sm[(sub * 8 + 5) * 260 + n] << 16);
        o.w = (unsigned)sm[(sub * 8 + 6) * 260 + n] | ((unsigned)sm[(sub * 8 + 7) * 260 + n] << 16);
        *(uint4*)&d[((size_t)kc * N + n0 + n) * 32 + sub * 8] = o;
    }
}

// ---------------------------------------------------------------------------
// 1) prep: blocks [0,2048) = W1 transpose; blocks [2048,3072) = fused
//    gate + scatter (1 token/wave; slot via global atomicAdd; writes Xg).
__global__ __launch_bounds__(256) void prep_kernel(
    const float* __restrict__ W1, ushort_t* __restrict__ W1T,
    const float* __restrict__ x, const float* __restrict__ Wg,
    const float* __restrict__ bg,
    int* __restrict__ cnt, int* __restrict__ slot_of,
    float* __restrict__ top_w, ushort_t* __restrict__ Xg)
{
    __shared__ __align__(16) ushort_t smem[32 * 260];
    const int b = blockIdx.x;
    const int tid = threadIdx.x;
    if (b < 2048) {
        // W1: K=1024 -> 32 kc; N=2048 -> 8 strips; 256 blocks/expert
        int e = b >> 8, idx = b & 255;
        wt_block(W1, W1T, e, idx >> 3, idx & 7, FFN, smem);
        return;
    }
    // --- fused gate + scatter ---
    const int g = b - 2048;
    const int lane = tid & 63, w = tid >> 6;
    const int t = g * 4 + w;
    const float* xr = x + (size_t)t * DMODEL;
    float acc[8] = {0.f,0.f,0.f,0.f,0.f,0.f,0.f,0.f};
    #pragma unroll
    for (int i = 0; i < 16; i++) {
        float xv = xr[i * 64 + lane];
        const float4* wp = (const float4*)&Wg[(i * 64 + lane) * 8];
        float4 a = wp[0], bb = wp[1];
        acc[0] += xv * a.x;  acc[1] += xv * a.y;
        acc[2] += xv * a.z;  acc[3] += xv * a.w;
        acc[4] += xv * bb.x; acc[5] += xv * bb.y;
        acc[6] += xv * bb.z; acc[7] += xv * bb.w;
    }
    #pragma unroll
    for (int off = 32; off > 0; off >>= 1) {
        #pragma unroll
        for (int e = 0; e < 8; e++) acc[e] += __shfl_down(acc[e], off);
    }
    int s0, s1;
    if (lane == 0) {
        float l[8];
        #pragma unroll
        for (int e = 0; e < 8; e++) l[e] = acc[e] + bg[e];
        int i0 = 0; float v0 = l[0];
        #pragma unroll
        for (int e = 1; e < 8; e++) if (l[e] > v0) { v0 = l[e]; i0 = e; }
        int i1 = -1; float v1 = -1e30f;
        #pragma unroll
        for (int e = 0; e < 8; e++) if (e != i0 && l[e] > v1) { v1 = l[e]; i1 = e; }
        float eg = expf(v1 - v0);
        float den = 1.f + eg;
        int p0 = atomicAdd(&cnt[i0], 1);
        int p1 = atomicAdd(&cnt[i1], 1);
        s0 = i0 * ECAP + p0;
        s1 = i1 * ECAP + p1;
        slot_of[2 * t]     = s0;
        slot_of[2 * t + 1] = s1;
        top_w[2 * t]     = 1.f / den;
        top_w[2 * t + 1] = eg / den;
    }
    s0 = __shfl(s0, 0);
    s1 = __shfl(s1, 0);
    // write both Xg copies (x row is L1-hot from the logit pass)
    #pragma unroll
    for (int j = 0; j < 4; j++) {
        int f = lane + j * 64;                     // float4 index 0..255
        float4 xv = ((const float4*)xr)[f];
        uint2 pk;
        pk.x = (unsigned)f2bf(xv.x) | ((unsigned)f2bf(xv.y) << 16);
        pk.y = (unsigned)f2bf(xv.z) | ((unsigned)f2bf(xv.w) << 16);
        ((uint2*)(Xg + (size_t)s0 * DMODEL))[f] = pk;
        ((uint2*)(Xg + (size_t)s1 * DMODEL))[f] = pk;
    }
}

// ---------------------------------------------------------------------------
// 2) grouped expert GEMM (v3 proven structure, BK=32):
//    C = A[M,K] * B + bias, bf16 out; B k-chunked [K/32][N][32].
//    FUSET: grid-z slices [MT1, MT1+16) perform W2 transpose blocks instead
//    (uniform per block; rides gemm1's idle HBM bandwidth).
template <int K, int N, bool RELU, bool FUSET>
__global__ __launch_bounds__(256) void expert_gemm(
    const ushort_t* __restrict__ A,
    const ushort_t* __restrict__ Bt,
    const float* __restrict__ bias,
    ushort_t* __restrict__ Cout,
    const int* __restrict__ cnt,
    const float* __restrict__ Wsrc,    // W2 (FUSET only)
    ushort_t* __restrict__ Wdst)       // W2T (FUSET only)
{
    __shared__ __align__(16) ushort_t smem[32 * 260];   // union: gemm uses 8192
    if (FUSET && blockIdx.z >= MT1) {
        // W2: K=2048 -> 64 kc; N=1024 -> 4 strips; 256 blocks/expert
        int idx = (blockIdx.z - MT1) * 128 + blockIdx.y * 8 + blockIdx.x; // [0,2048)
        int e = idx >> 8, r = idx & 255;
        wt_block(Wsrc, Wdst, e, r >> 2, r & 3, DMODEL, smem);
        return;
    }
    const int e  = blockIdx.x;
    const int nt = blockIdx.y;
    const int mt = blockIdx.z;
    const int off_e = e * ECAP;
    if (mt * 128 >= cnt[e]) return;

    ushort_t* As = smem;            // 128*32
    ushort_t* Bs = smem + 4096;     // 128*32

    const int tid  = threadIdx.x;
    const int lane = tid & 63;
    const int w    = tid >> 6;
    const int quad = lane >> 4;
    const int r16  = lane & 15;
    const int lrow = lane >> 2;                          // staging row 0..15
    const int lk   = (((lane & 3) ^ ((lane >> 3) & 3))) * 8;  // swizzled src k

    const size_t arow0 = (size_t)(off_e + mt * 128);
    const ushort_t* aS0 = A + (arow0 + (size_t)(2 * w + 0) * 16 + lrow) * K + lk;
    const ushort_t* aS1 = A + (arow0 + (size_t)(2 * w + 1) * 16 + lrow) * K + lk;
    const ushort_t* Bte = Bt + (size_t)e * N * K;
    // k-chunked B: element (kc, n, ks) at kc*N*32 + n*32 + ks; kc*N*32 == k0*N
    const ushort_t* bS0 = Bte + (size_t)(nt * 128 + (2 * w + 0) * 16 + lrow) * 32 + lk;
    const ushort_t* bS1 = Bte + (size_t)(nt * 128 + (2 * w + 1) * 16 + lrow) * 32 + lk;
    ushort_t* aD0 = &As[(2 * w + 0) * 512];
    ushort_t* aD1 = &As[(2 * w + 1) * 512];
    ushort_t* bD0 = &Bs[(2 * w + 0) * 512];
    ushort_t* bD1 = &Bs[(2 * w + 1) * 512];

    const int wm = (w >> 1) * 64;
    const int wn = (w & 1) * 64;
    const int sw = ((r16 >> 1) & 3) ^ quad;   // swizzled read chunk

    f32x4 acc[4][4];
    #pragma unroll
    for (int i = 0; i < 4; i++)
        #pragma unroll
        for (int j = 0; j < 4; j++)
            acc[i][j] = (f32x4){0.f, 0.f, 0.f, 0.f};

    for (int k0 = 0; k0 < K; k0 += 32) {
        gload_lds16(aS0 + k0, aD0);
        gload_lds16(aS1 + k0, aD1);
        gload_lds16(bS0 + (size_t)k0 * N, bD0);
        gload_lds16(bS1 + (size_t)k0 * N, bD1);
        __syncthreads();
        short8 af[4], bfr[4];
        #pragma unroll
        for (int i = 0; i < 4; i++)
            af[i] = *(const short8*)&As[(wm + i * 16 + r16) * 32 + sw * 8];
        #pragma unroll
        for (int j = 0; j < 4; j++)
            bfr[j] = *(const short8*)&Bs[(wn + j * 16 + r16) * 32 + sw * 8];
        #pragma unroll
        for (int i = 0; i < 4; i++)
            #pragma unroll
            for (int j = 0; j < 4; j++)
                acc[i][j] = __builtin_amdgcn_mfma_f32_16x16x32_bf16(
                    af[i], bfr[j], acc[i][j], 0, 0, 0);
        __syncthreads();
    }

    const float* be = bias + (size_t)e * N;
    #pragma unroll
    for (int i = 0; i < 4; i++) {
        #pragma unroll
        for (int j = 0; j < 4; j++) {
            int n = nt * 128 + wn + j * 16 + r16;
            float bv = be[n];
            #pragma unroll
            for (int r = 0; r < 4; r++) {
                int m = mt * 128 + wm + i * 16 + quad * 4 + r;
                float v = acc[i][j][r] + bv;
                if (RELU) v = v > 0.f ? v : 0.f;
                Cout[(size_t)(off_e + m) * N + n] = f2bf(v);
            }
        }
    }
}

// ---------------------------------------------------------------------------
// 3) fused mix + residual + LayerNorm
__global__ __launch_bounds__(256) void ln_kernel(
    const float* __restrict__ x, const ushort_t* __restrict__ O,
    const int* __restrict__ slot_of, const float* __restrict__ top_w,
    const float* __restrict__ gamma, const float* __restrict__ beta,
    float* __restrict__ out)
{
    int t = blockIdx.x, tid = threadIdx.x;
    int s0 = slot_of[2 * t], s1 = slot_of[2 * t + 1];
    float w0 = top_w[2 * t], w1 = top_w[2 * t + 1];
    float4 xv = ((const float4*)(x + (size_t)t * DMODEL))[tid];
    uint2 a = ((const uint2*)(O + (size_t)s0 * DMODEL))[tid];
    uint2 b = ((const uint2*)(O + (size_t)s1 * DMODEL))[tid];

    float y[4];
    y[0] = xv.x + w0 * bflo(a.x) + w1 * bflo(b.x);
    y[1] = xv.y + w0 * bfhi(a.x) + w1 * bfhi(b.x);
    y[2] = xv.z + w0 * bflo(a.y) + w1 * bflo(b.y);
    y[3] = xv.w + w0 * bfhi(a.y) + w1 * bfhi(b.y);

    float s = y[0] + y[1] + y[2] + y[3];
    float sq = y[0]*y[0] + y[1]*y[1] + y[2]*y[2] + y[3]*y[3];
    __shared__ float red[2][4];
    #pragma unroll
    for (int off = 32; off > 0; off >>= 1) {
        s += __shfl_down(s, off);
        sq += __shfl_down(sq, off);
    }
    int lane = tid & 63, wv = tid >> 6;
    if (lane == 0) { red[0][wv] = s; red[1][wv] = sq; }
    __syncthreads();
    if (tid == 0) {
        float S = red[0][0] + red[0][1] + red[0][2] + red[0][3];
        float SQ = red[1][0] + red[1][1] + red[1][2] + red[1][3];
        float mu = S * (1.f / DMODEL);
        float var = SQ * (1.f / DMODEL) - mu * mu;
        red[0][0] = mu;
        red[1][0] = rsqrtf(var + 1e-5f);
    }
    __syncthreads();
    float mu = red[0][0], inv = red[1][0];
    float4 gv = ((const float4*)gamma)[tid];
    float4 bv = ((const float4*)beta)[tid];
    float4 ov;
    ov.x = gv.x * (y[0] - mu) * inv + bv.x;
    ov.y = gv.y * (y[1] - mu) * inv + bv.y;
    ov.z = gv.z * (y[2] - mu) * inv + bv.z;
    ov.w = gv.w * (y[3] - mu) * inv + bv.w;
    ((float4*)(out + (size_t)t * DMODEL))[tid] = ov;
}

// ---------------------------------------------------------------------------
extern "C" void kernel_launch(void* const* d_in, const int* in_sizes, int n_in,
                              void* d_out, int out_size, void* d_ws, size_t ws_size,
                              hipStream_t stream)
{
    const float* x     = (const float*)d_in[0];
    const float* Wg    = (const float*)d_in[1];
    const float* bg    = (const float*)d_in[2];
    const float* W1    = (const float*)d_in[3];
    const float* b1    = (const float*)d_in[4];
    const float* W2    = (const float*)d_in[5];
    const float* b2    = (const float*)d_in[6];
    const float* gamma = (const float*)d_in[7];
    const float* beta  = (const float*)d_in[8];
    float* out = (float*)d_out;

    char* ws = (char*)d_ws;
    size_t o = 0;
    auto alloc = [&](size_t bytes) {
        size_t r = o;
        o = (o + bytes + 255) & ~(size_t)255;
        return r;
    };
    size_t o_cnt     = alloc(NEXP * 4);
    size_t o_topw    = alloc((size_t)T_TOKENS * 2 * 4);
    size_t o_slotof  = alloc((size_t)T_TOKENS * 2 * 4);
    size_t o_w1t     = alloc((size_t)NEXP * DMODEL * FFN * 2);
    size_t o_w2t     = alloc((size_t)NEXP * DMODEL * FFN * 2);
    size_t o_xg      = alloc((size_t)MAXSLOTS * DMODEL * 2);
    size_t o_h       = alloc((size_t)MAXSLOTS * FFN * 2);
    size_t o_obuf    = alloc((size_t)MAXSLOTS * DMODEL * 2);
    (void)ws_size; (void)in_sizes; (void)n_in; (void)out_size;

    int*      cnt      = (int*)(ws + o_cnt);
    float*    top_w    = (float*)(ws + o_topw);
    int*      slot_of  = (int*)(ws + o_slotof);
    ushort_t* W1T      = (ushort_t*)(ws + o_w1t);
    ushort_t* W2T      = (ushort_t*)(ws + o_w2t);
    ushort_t* Xg       = (ushort_t*)(ws + o_xg);
    ushort_t* H        = (ushort_t*)(ws + o_h);
    ushort_t* Obuf     = (ushort_t*)(ws + o_obuf);

    hipMemsetAsync(cnt, 0, NEXP * sizeof(int), stream);
    prep_kernel<<<3072, 256, 0, stream>>>(W1, W1T, x, Wg, bg,
                                          cnt, slot_of, top_w, Xg);
    expert_gemm<DMODEL, FFN, true, true>
        <<<dim3(NEXP, FFN / 128, MT1 + 16), 256, 0, stream>>>(
            Xg, W1T, b1, H, cnt, W2, W2T);
    expert_gemm<FFN, DMODEL, false, false>
        <<<dim3(NEXP, DMODEL / 128, MT1), 256, 0, stream>>>(
            H, W2T, b2, Obuf, cnt, nullptr, nullptr);
    ln_kernel<<<T_TOKENS, 256, 0, stream>>>(x, Obuf, slot_of, top_w, gamma, beta, out);
}

// Round 6
// 302.471 us; speedup vs baseline: 1.2449x; 1.2449x over previous
//
#include <hip/hip_runtime.h>

// ---------------------------------------------------------------------------
// MoE block: x[2,2048,1024] fp32, 8 experts, top-2 routing, f=2048, LN output.
// v11: v10's prep was serialized by 8192 device-scope atomicAdds on ONE cache
//      line (127us, all pipes idle). Fix: 16 tokens/block gate with LDS
//      histogram + ONE padded global atomic per expert per block (2048 atomics
//      over 8 distinct 64B lines). Both W1T and W2T transposes back in prep
//      (v9's proven 512-strip geometry, 68us for both); gemm1 reverts to the
//      pure proven v3 GEMM loop. 4 kernels + 512B memset.
// ---------------------------------------------------------------------------

typedef unsigned short ushort_t;
typedef short short8 __attribute__((ext_vector_type(8)));
typedef float f32x4 __attribute__((ext_vector_type(4)));

#define T_TOKENS 4096
#define DMODEL 1024
#define FFN 2048
#define NEXP 8
#define ECAP 1152          // fixed slot capacity per expert (8*1152 = 9216)
#define MAXSLOTS 9216
#define MT1 9              // ceil(ECAP/128)
#define CNT_STRIDE 16      // ints: 64B between counters (one line each)
#define GATE_BLKS 256      // 16 tokens per block

__device__ __forceinline__ ushort_t f2bf(float f) {
    unsigned u = __float_as_uint(f);
    return (ushort_t)((u + 0x7fffu + ((u >> 16) & 1u)) >> 16);
}
__device__ __forceinline__ float bflo(unsigned packed) {
    return __uint_as_float(packed << 16);
}
__device__ __forceinline__ float bfhi(unsigned packed) {
    return __uint_as_float(packed & 0xffff0000u);
}

__device__ __forceinline__ void gload_lds16(const void* g, void* l) {
    __builtin_amdgcn_global_load_lds(
        (const __attribute__((address_space(1))) unsigned int*)g,
        (__attribute__((address_space(3))) unsigned int*)l,
        16, 0, 0);
}

// ---------------------------------------------------------------------------
// 1) prep: blocks [0,256) = gate (16 tokens each, LDS-aggregated routing,
//    writes Xg); blocks [256,2304) = W1/W2 transpose into k-chunked layout
//    Wt[K/32][N][32] bf16 (v9 proven geometry: 512-wide strips, contiguous
//    reads 2KB/row-visit, one contiguous 32KB write range per block).
__global__ __launch_bounds__(256) void prep_kernel(
    const float* __restrict__ W1, ushort_t* __restrict__ W1T,
    const float* __restrict__ W2, ushort_t* __restrict__ W2T,
    const float* __restrict__ x, const float* __restrict__ Wg,
    const float* __restrict__ bg,
    int* __restrict__ gcnt, int* __restrict__ slot_of,
    float* __restrict__ top_w, ushort_t* __restrict__ Xg)
{
    __shared__ __align__(16) ushort_t smem[32 * 516];   // 33 KB
    const int b = blockIdx.x;
    const int tid = threadIdx.x;

    if (b >= GATE_BLKS) {
        // ---------------- transpose part ----------------
        int b2 = b - GATE_BLKS;
        const float* s; ushort_t* d; int N, kc, ns;
        if (b2 < 1024) {            // W1: K=1024 (32 kc), N=2048 (4 strips)
            int e = b2 >> 7, idx = b2 & 127;
            kc = idx >> 2; ns = idx & 3;
            s = W1 + (size_t)e * DMODEL * FFN;
            d = W1T + (size_t)e * DMODEL * FFN;
            N = FFN;
        } else {                    // W2: K=2048 (64 kc), N=1024 (2 strips)
            b2 -= 1024;
            int e = b2 >> 7, idx = b2 & 127;
            kc = idx >> 1; ns = idx & 1;
            s = W2 + (size_t)e * DMODEL * FFN;
            d = W2T + (size_t)e * DMODEL * FFN;
            N = DMODEL;
        }
        const int k0 = kc * 32, n0 = ns * 512;
        ushort_t* lt = smem;                 // [32][516]
        #pragma unroll
        for (int i = 0; i < 16; i++) {
            int k = i * 2 + (tid >> 7);      // 0..31
            int n = (tid & 127) * 4;         // 0..508
            float4 v = *(const float4*)&s[(size_t)(k0 + k) * N + n0 + n];
            uint2 pk;
            pk.x = (unsigned)f2bf(v.x) | ((unsigned)f2bf(v.y) << 16);
            pk.y = (unsigned)f2bf(v.z) | ((unsigned)f2bf(v.w) << 16);
            *(uint2*)&lt[k * 516 + n] = pk;
        }
        __syncthreads();
        const int sub = tid & 3;
        const int nl0 = tid >> 2;            // 0..63
        #pragma unroll
        for (int it = 0; it < 8; it++) {
            int n = nl0 + it * 64;           // 0..511
            uint4 o;
            o.x = (unsigned)lt[(sub * 8 + 0) * 516 + n] | ((unsigned)lt[(sub * 8 + 1) * 516 + n] << 16);
            o.y = (unsigned)lt[(sub * 8 + 2) * 516 + n] | ((unsigned)lt[(sub * 8 + 3) * 516 + n] << 16);
            o.z = (unsigned)lt[(sub * 8 + 4) * 516 + n] | ((unsigned)lt[(sub * 8 + 5) * 516 + n] << 16);
            o.w = (unsigned)lt[(sub * 8 + 6) * 516 + n] | ((unsigned)lt[(sub * 8 + 7) * 516 + n] << 16);
            *(uint4*)&d[((size_t)kc * N + n0 + n) * 32 + sub * 8] = o;
        }
        return;
    }

    // ---------------- gate part: 16 tokens, LDS-aggregated routing ----------
    int* sh    = (int*)smem;
    int* hist  = sh;          // [8]  per-expert count in this block
    int* sbase = sh + 8;      // [8]  global base from one atomic per expert
    int* tokinf = sh + 16;    // [32] per token: e | (localpos << 4), 2 entries
    const int lane = tid & 63, w = tid >> 6;
    if (tid < NEXP) hist[tid] = 0;
    __syncthreads();

    #pragma unroll 1
    for (int it = 0; it < 4; it++) {
        const int t = b * 16 + w * 4 + it;
        const float* xr = x + (size_t)t * DMODEL;
        float acc[8] = {0.f,0.f,0.f,0.f,0.f,0.f,0.f,0.f};
        #pragma unroll
        for (int i = 0; i < 16; i++) {
            float xv = xr[i * 64 + lane];
            const float4* wp = (const float4*)&Wg[(i * 64 + lane) * 8];
            float4 a = wp[0], bb = wp[1];
            acc[0] += xv * a.x;  acc[1] += xv * a.y;
            acc[2] += xv * a.z;  acc[3] += xv * a.w;
            acc[4] += xv * bb.x; acc[5] += xv * bb.y;
            acc[6] += xv * bb.z; acc[7] += xv * bb.w;
        }
        #pragma unroll
        for (int off = 32; off > 0; off >>= 1) {
            #pragma unroll
            for (int e = 0; e < 8; e++) acc[e] += __shfl_down(acc[e], off);
        }
        if (lane == 0) {
            float l[8];
            #pragma unroll
            for (int e = 0; e < 8; e++) l[e] = acc[e] + bg[e];
            int i0 = 0; float v0 = l[0];
            #pragma unroll
            for (int e = 1; e < 8; e++) if (l[e] > v0) { v0 = l[e]; i0 = e; }
            int i1 = -1; float v1 = -1e30f;
            #pragma unroll
            for (int e = 0; e < 8; e++) if (e != i0 && l[e] > v1) { v1 = l[e]; i1 = e; }
            float eg = expf(v1 - v0);
            float den = 1.f + eg;
            top_w[2 * t]     = 1.f / den;
            top_w[2 * t + 1] = eg / den;
            int p0 = atomicAdd(&hist[i0], 1);
            int p1 = atomicAdd(&hist[i1], 1);
            tokinf[(w * 4 + it) * 2 + 0] = i0 | (p0 << 4);
            tokinf[(w * 4 + it) * 2 + 1] = i1 | (p1 << 4);
        }
    }
    __syncthreads();
    if (tid < NEXP) sbase[tid] = atomicAdd(&gcnt[tid * CNT_STRIDE], hist[tid]);
    __syncthreads();

    #pragma unroll 1
    for (int it = 0; it < 4; it++) {
        const int t = b * 16 + w * 4 + it;
        int v0 = tokinf[(w * 4 + it) * 2 + 0];
        int v1 = tokinf[(w * 4 + it) * 2 + 1];
        int e0 = v0 & 15, e1 = v1 & 15;
        int s0 = e0 * ECAP + sbase[e0] + (v0 >> 4);
        int s1 = e1 * ECAP + sbase[e1] + (v1 >> 4);
        if (lane == 0) {
            slot_of[2 * t]     = s0;
            slot_of[2 * t + 1] = s1;
        }
        const float* xr = x + (size_t)t * DMODEL;
        #pragma unroll
        for (int j = 0; j < 4; j++) {
            int f = lane + j * 64;                 // float4 index 0..255
            float4 xv = ((const float4*)xr)[f];
            uint2 pk;
            pk.x = (unsigned)f2bf(xv.x) | ((unsigned)f2bf(xv.y) << 16);
            pk.y = (unsigned)f2bf(xv.z) | ((unsigned)f2bf(xv.w) << 16);
            ((uint2*)(Xg + (size_t)s0 * DMODEL))[f] = pk;
            ((uint2*)(Xg + (size_t)s1 * DMODEL))[f] = pk;
        }
    }
}

// ---------------------------------------------------------------------------
// 2) grouped expert GEMM (v3 proven structure, BK=32, 16KB LDS):
//    C = A[M,K] * B + bias, bf16 out; B k-chunked [K/32][N][32].
//    gridDim.x = 8 = expert (XCD pin). XOR-swizzled LDS chunks.
template <int K, int N, bool RELU>
__global__ __launch_bounds__(256) void expert_gemm(
    const ushort_t* __restrict__ A,
    const ushort_t* __restrict__ Bt,
    const float* __restrict__ bias,
    ushort_t* __restrict__ Cout,
    const int* __restrict__ gcnt)
{
    const int e  = blockIdx.x;
    const int nt = blockIdx.y;
    const int mt = blockIdx.z;
    const int off_e = e * ECAP;
    if (mt * 128 >= gcnt[e * CNT_STRIDE]) return;

    __shared__ __align__(16) ushort_t As[128 * 32];
    __shared__ __align__(16) ushort_t Bs[128 * 32];

    const int tid  = threadIdx.x;
    const int lane = tid & 63;
    const int w    = tid >> 6;
    const int quad = lane >> 4;
    const int r16  = lane & 15;
    const int lrow = lane >> 2;                          // staging row 0..15
    const int lk   = (((lane & 3) ^ ((lane >> 3) & 3))) * 8;  // swizzled src k

    const size_t arow0 = (size_t)(off_e + mt * 128);
    const ushort_t* aS0 = A + (arow0 + (size_t)(2 * w + 0) * 16 + lrow) * K + lk;
    const ushort_t* aS1 = A + (arow0 + (size_t)(2 * w + 1) * 16 + lrow) * K + lk;
    const ushort_t* Bte = Bt + (size_t)e * N * K;
    // k-chunked B: element (kc, n, ks) at kc*N*32 + n*32 + ks; kc*N*32 == k0*N
    const ushort_t* bS0 = Bte + (size_t)(nt * 128 + (2 * w + 0) * 16 + lrow) * 32 + lk;
    const ushort_t* bS1 = Bte + (size_t)(nt * 128 + (2 * w + 1) * 16 + lrow) * 32 + lk;
    ushort_t* aD0 = &As[(2 * w + 0) * 512];
    ushort_t* aD1 = &As[(2 * w + 1) * 512];
    ushort_t* bD0 = &Bs[(2 * w + 0) * 512];
    ushort_t* bD1 = &Bs[(2 * w + 1) * 512];

    const int wm = (w >> 1) * 64;
    const int wn = (w & 1) * 64;
    const int sw = ((r16 >> 1) & 3) ^ quad;   // swizzled read chunk

    f32x4 acc[4][4];
    #pragma unroll
    for (int i = 0; i < 4; i++)
        #pragma unroll
        for (int j = 0; j < 4; j++)
            acc[i][j] = (f32x4){0.f, 0.f, 0.f, 0.f};

    for (int k0 = 0; k0 < K; k0 += 32) {
        gload_lds16(aS0 + k0, aD0);
        gload_lds16(aS1 + k0, aD1);
        gload_lds16(bS0 + (size_t)k0 * N, bD0);
        gload_lds16(bS1 + (size_t)k0 * N, bD1);
        __syncthreads();
        short8 af[4], bfr[4];
        #pragma unroll
        for (int i = 0; i < 4; i++)
            af[i] = *(const short8*)&As[(wm + i * 16 + r16) * 32 + sw * 8];
        #pragma unroll
        for (int j = 0; j < 4; j++)
            bfr[j] = *(const short8*)&Bs[(wn + j * 16 + r16) * 32 + sw * 8];
        #pragma unroll
        for (int i = 0; i < 4; i++)
            #pragma unroll
            for (int j = 0; j < 4; j++)
                acc[i][j] = __builtin_amdgcn_mfma_f32_16x16x32_bf16(
                    af[i], bfr[j], acc[i][j], 0, 0, 0);
        __syncthreads();
    }

    const float* be = bias + (size_t)e * N;
    #pragma unroll
    for (int i = 0; i < 4; i++) {
        #pragma unroll
        for (int j = 0; j < 4; j++) {
            int n = nt * 128 + wn + j * 16 + r16;
            float bv = be[n];
            #pragma unroll
            for (int r = 0; r < 4; r++) {
                int m = mt * 128 + wm + i * 16 + quad * 4 + r;
                float v = acc[i][j][r] + bv;
                if (RELU) v = v > 0.f ? v : 0.f;
                Cout[(size_t)(off_e + m) * N + n] = f2bf(v);
            }
        }
    }
}

// ---------------------------------------------------------------------------
// 3) fused mix + residual + LayerNorm
__global__ __launch_bounds__(256) void ln_kernel(
    const float* __restrict__ x, const ushort_t* __restrict__ O,
    const int* __restrict__ slot_of, const float* __restrict__ top_w,
    const float* __restrict__ gamma, const float* __restrict__ beta,
    float* __restrict__ out)
{
    int t = blockIdx.x, tid = threadIdx.x;
    int s0 = slot_of[2 * t], s1 = slot_of[2 * t + 1];
    float w0 = top_w[2 * t], w1 = top_w[2 * t + 1];
    float4 xv = ((const float4*)(x + (size_t)t * DMODEL))[tid];
    uint2 a = ((const uint2*)(O + (size_t)s0 * DMODEL))[tid];
    uint2 b = ((const uint2*)(O + (size_t)s1 * DMODEL))[tid];

    float y[4];
    y[0] = xv.x + w0 * bflo(a.x) + w1 * bflo(b.x);
    y[1] = xv.y + w0 * bfhi(a.x) + w1 * bfhi(b.x);
    y[2] = xv.z + w0 * bflo(a.y) + w1 * bflo(b.y);
    y[3] = xv.w + w0 * bfhi(a.y) + w1 * bfhi(b.y);

    float s = y[0] + y[1] + y[2] + y[3];
    float sq = y[0]*y[0] + y[1]*y[1] + y[2]*y[2] + y[3]*y[3];
    __shared__ float red[2][4];
    #pragma unroll
    for (int off = 32; off > 0; off >>= 1) {
        s += __shfl_down(s, off);
        sq += __shfl_down(sq, off);
    }
    int lane = tid & 63, wv = tid >> 6;
    if (lane == 0) { red[0][wv] = s; red[1][wv] = sq; }
    __syncthreads();
    if (tid == 0) {
        float S = red[0][0] + red[0][1] + red[0][2] + red[0][3];
        float SQ = red[1][0] + red[1][1] + red[1][2] + red[1][3];
        float mu = S * (1.f / DMODEL);
        float var = SQ * (1.f / DMODEL) - mu * mu;
        red[0][0] = mu;
        red[1][0] = rsqrtf(var + 1e-5f);
    }
    __syncthreads();
    float mu = red[0][0], inv = red[1][0];
    float4 gv = ((const float4*)gamma)[tid];
    float4 bv = ((const float4*)beta)[tid];
    float4 ov;
    ov.x = gv.x * (y[0] - mu) * inv + bv.x;
    ov.y = gv.y * (y[1] - mu) * inv + bv.y;
    ov.z = gv.z * (y[2] - mu) * inv + bv.z;
    ov.w = gv.w * (y[3] - mu) * inv + bv.w;
    ((float4*)(out + (size_t)t * DMODEL))[tid] = ov;
}

// ---------------------------------------------------------------------------
extern "C" void kernel_launch(void* const* d_in, const int* in_sizes, int n_in,
                              void* d_out, int out_size, void* d_ws, size_t ws_size,
                              hipStream_t stream)
{
    const float* x     = (const float*)d_in[0];
    const float* Wg    = (const float*)d_in[1];
    const float* bg    = (const float*)d_in[2];
    const float* W1    = (const float*)d_in[3];
    const float* b1    = (const float*)d_in[4];
    const float* W2    = (const float*)d_in[5];
    const float* b2    = (const float*)d_in[6];
    const float* gamma = (const float*)d_in[7];
    const float* beta  = (const float*)d_in[8];
    float* out = (float*)d_out;

    char* ws = (char*)d_ws;
    size_t o = 0;
    auto alloc = [&](size_t bytes) {
        size_t r = o;
        o = (o + bytes + 255) & ~(size_t)255;
        return r;
    };
    size_t o_cnt     = alloc(NEXP * CNT_STRIDE * 4);
    size_t o_topw    = alloc((size_t)T_TOKENS * 2 * 4);
    size_t o_slotof  = alloc((size_t)T_TOKENS * 2 * 4);
    size_t o_w1t     = alloc((size_t)NEXP * DMODEL * FFN * 2);
    size_t o_w2t     = alloc((size_t)NEXP * DMODEL * FFN * 2);
    size_t o_xg      = alloc((size_t)MAXSLOTS * DMODEL * 2);
    size_t o_h       = alloc((size_t)MAXSLOTS * FFN * 2);
    size_t o_obuf    = alloc((size_t)MAXSLOTS * DMODEL * 2);
    (void)ws_size; (void)in_sizes; (void)n_in; (void)out_size;

    int*      gcnt     = (int*)(ws + o_cnt);
    float*    top_w    = (float*)(ws + o_topw);
    int*      slot_of  = (int*)(ws + o_slotof);
    ushort_t* W1T      = (ushort_t*)(ws + o_w1t);
    ushort_t* W2T      = (ushort_t*)(ws + o_w2t);
    ushort_t* Xg       = (ushort_t*)(ws + o_xg);
    ushort_t* H        = (ushort_t*)(ws + o_h);
    ushort_t* Obuf     = (ushort_t*)(ws + o_obuf);

    hipMemsetAsync(gcnt, 0, NEXP * CNT_STRIDE * sizeof(int), stream);
    prep_kernel<<<GATE_BLKS + 2048, 256, 0, stream>>>(
        W1, W1T, W2, W2T, x, Wg, bg, gcnt, slot_of, top_w, Xg);
    expert_gemm<DMODEL, FFN, true>
        <<<dim3(NEXP, FFN / 128, MT1), 256, 0, stream>>>(Xg, W1T, b1, H, gcnt);
    expert_gemm<FFN, DMODEL, false>
        <<<dim3(NEXP, DMODEL / 128, MT1), 256, 0, stream>>>(H, W2T, b2, Obuf, gcnt);
    ln_kernel<<<T_TOKENS, 256, 0, stream>>>(x, Obuf, slot_of, top_w, gamma, beta, out);
}

// Round 7
// 294.574 us; speedup vs baseline: 1.2783x; 1.0268x over previous
//
#include <hip/hip_runtime.h>

// ---------------------------------------------------------------------------
// MoE block: x[2,2048,1024] fp32, 8 experts, top-2 routing, f=2048, LN output.
// v12: W2T transpose moved from prep into gemm1's grid with FINE-GRAINED
//      1-D interleave (every 17 blocks = 9 gemm + 8 transpose) so both are
//      co-resident (v10's z-slice fusion serialized: z varies slowest, all
//      transpose blocks dispatched after all gemm blocks). prep = gate + W1T
//      only. gemm2 unchanged -> becomes visible in top-5 for next round.
//      Routing: v11's proven block-aggregated padded atomics.
// ---------------------------------------------------------------------------

typedef unsigned short ushort_t;
typedef short short8 __attribute__((ext_vector_type(8)));
typedef float f32x4 __attribute__((ext_vector_type(4)));

#define T_TOKENS 4096
#define DMODEL 1024
#define FFN 2048
#define NEXP 8
#define ECAP 1152          // fixed slot capacity per expert (8*1152 = 9216)
#define MAXSLOTS 9216
#define MT1 9              // ceil(ECAP/128)
#define CNT_STRIDE 16      // ints: 64B between counters (one line each)
#define GATE_BLKS 256      // 16 tokens per block

__device__ __forceinline__ ushort_t f2bf(float f) {
    unsigned u = __float_as_uint(f);
    return (ushort_t)((u + 0x7fffu + ((u >> 16) & 1u)) >> 16);
}
__device__ __forceinline__ float bflo(unsigned packed) {
    return __uint_as_float(packed << 16);
}
__device__ __forceinline__ float bfhi(unsigned packed) {
    return __uint_as_float(packed & 0xffff0000u);
}

__device__ __forceinline__ void gload_lds16(const void* g, void* l) {
    __builtin_amdgcn_global_load_lds(
        (const __attribute__((address_space(1))) unsigned int*)g,
        (__attribute__((address_space(3))) unsigned int*)l,
        16, 0, 0);
}

// ---------------------------------------------------------------------------
// k-chunked transpose block (v9/v11 proven 512-strip geometry):
// Wsrc[K,N] fp32 -> Wdst[K/32][N][32] bf16 for one (kc, 512-wide n-strip).
// Contiguous 2KB reads per row-visit; ONE contiguous 32KB write range
// (complete 64B sectors per store instr). lt = LDS [32][516] ushorts.
__device__ __forceinline__ void wt_block512(
    const float* __restrict__ s, ushort_t* __restrict__ d,
    int N, int kc, int n0, ushort_t* lt, int tid)
{
    const int k0 = kc * 32;
    #pragma unroll
    for (int i = 0; i < 16; i++) {
        int k = i * 2 + (tid >> 7);        // 0..31
        int n = (tid & 127) * 4;           // 0..508
        float4 v = *(const float4*)&s[(size_t)(k0 + k) * N + n0 + n];
        uint2 pk;
        pk.x = (unsigned)f2bf(v.x) | ((unsigned)f2bf(v.y) << 16);
        pk.y = (unsigned)f2bf(v.z) | ((unsigned)f2bf(v.w) << 16);
        *(uint2*)&lt[k * 516 + n] = pk;
    }
    __syncthreads();
    const int sub = tid & 3;
    const int nl0 = tid >> 2;              // 0..63
    #pragma unroll
    for (int it = 0; it < 8; it++) {
        int n = nl0 + it * 64;             // 0..511
        uint4 o;
        o.x = (unsigned)lt[(sub * 8 + 0) * 516 + n] | ((unsigned)lt[(sub * 8 + 1) * 516 + n] << 16);
        o.y = (unsigned)lt[(sub * 8 + 2) * 516 + n] | ((unsigned)lt[(sub * 8 + 3) * 516 + n] << 16);
        o.z = (unsigned)lt[(sub * 8 + 4) * 516 + n] | ((unsigned)lt[(sub * 8 + 5) * 516 + n] << 16);
        o.w = (unsigned)lt[(sub * 8 + 6) * 516 + n] | ((unsigned)lt[(sub * 8 + 7) * 516 + n] << 16);
        *(uint4*)&d[((size_t)kc * N + n0 + n) * 32 + sub * 8] = o;
    }
}

// ---------------------------------------------------------------------------
// 1) prep: blocks [0,256) = gate (16 tokens each, LDS-aggregated routing,
//    one padded global atomic per expert per block, writes Xg);
//    blocks [256,1280) = W1 transpose (k-chunked, 512-strips).
__global__ __launch_bounds__(256) void prep_kernel(
    const float* __restrict__ W1, ushort_t* __restrict__ W1T,
    const float* __restrict__ x, const float* __restrict__ Wg,
    const float* __restrict__ bg,
    int* __restrict__ gcnt, int* __restrict__ slot_of,
    float* __restrict__ top_w, ushort_t* __restrict__ Xg)
{
    __shared__ __align__(16) ushort_t smem[32 * 516];   // 33 KB
    const int b = blockIdx.x;
    const int tid = threadIdx.x;

    if (b >= GATE_BLKS) {
        // W1: K=1024 -> 32 kc; N=2048 -> 4 strips; 128 blocks/expert
        int b2 = b - GATE_BLKS;
        int e = b2 >> 7, idx = b2 & 127;
        wt_block512(W1 + (size_t)e * DMODEL * FFN,
                    W1T + (size_t)e * DMODEL * FFN,
                    FFN, idx >> 2, (idx & 3) * 512, smem, tid);
        return;
    }

    // ---------------- gate part: 16 tokens, LDS-aggregated routing ----------
    int* sh    = (int*)smem;
    int* hist  = sh;          // [8]  per-expert count in this block
    int* sbase = sh + 8;      // [8]  global base from one atomic per expert
    int* tokinf = sh + 16;    // [32] per token: e | (localpos << 4), 2 entries
    const int lane = tid & 63, w = tid >> 6;
    if (tid < NEXP) hist[tid] = 0;
    __syncthreads();

    #pragma unroll 1
    for (int it = 0; it < 4; it++) {
        const int t = b * 16 + w * 4 + it;
        const float* xr = x + (size_t)t * DMODEL;
        float acc[8] = {0.f,0.f,0.f,0.f,0.f,0.f,0.f,0.f};
        #pragma unroll
        for (int i = 0; i < 16; i++) {
            float xv = xr[i * 64 + lane];
            const float4* wp = (const float4*)&Wg[(i * 64 + lane) * 8];
            float4 a = wp[0], bb = wp[1];
            acc[0] += xv * a.x;  acc[1] += xv * a.y;
            acc[2] += xv * a.z;  acc[3] += xv * a.w;
            acc[4] += xv * bb.x; acc[5] += xv * bb.y;
            acc[6] += xv * bb.z; acc[7] += xv * bb.w;
        }
        #pragma unroll
        for (int off = 32; off > 0; off >>= 1) {
            #pragma unroll
            for (int e = 0; e < 8; e++) acc[e] += __shfl_down(acc[e], off);
        }
        if (lane == 0) {
            float l[8];
            #pragma unroll
            for (int e = 0; e < 8; e++) l[e] = acc[e] + bg[e];
            int i0 = 0; float v0 = l[0];
            #pragma unroll
            for (int e = 1; e < 8; e++) if (l[e] > v0) { v0 = l[e]; i0 = e; }
            int i1 = -1; float v1 = -1e30f;
            #pragma unroll
            for (int e = 0; e < 8; e++) if (e != i0 && l[e] > v1) { v1 = l[e]; i1 = e; }
            float eg = expf(v1 - v0);
            float den = 1.f + eg;
            top_w[2 * t]     = 1.f / den;
            top_w[2 * t + 1] = eg / den;
            int p0 = atomicAdd(&hist[i0], 1);
            int p1 = atomicAdd(&hist[i1], 1);
            tokinf[(w * 4 + it) * 2 + 0] = i0 | (p0 << 4);
            tokinf[(w * 4 + it) * 2 + 1] = i1 | (p1 << 4);
        }
    }
    __syncthreads();
    if (tid < NEXP) sbase[tid] = atomicAdd(&gcnt[tid * CNT_STRIDE], hist[tid]);
    __syncthreads();

    #pragma unroll 1
    for (int it = 0; it < 4; it++) {
        const int t = b * 16 + w * 4 + it;
        int v0 = tokinf[(w * 4 + it) * 2 + 0];
        int v1 = tokinf[(w * 4 + it) * 2 + 1];
        int e0 = v0 & 15, e1 = v1 & 15;
        int s0 = e0 * ECAP + sbase[e0] + (v0 >> 4);
        int s1 = e1 * ECAP + sbase[e1] + (v1 >> 4);
        if (lane == 0) {
            slot_of[2 * t]     = s0;
            slot_of[2 * t + 1] = s1;
        }
        const float* xr = x + (size_t)t * DMODEL;
        #pragma unroll
        for (int j = 0; j < 4; j++) {
            int f = lane + j * 64;                 // float4 index 0..255
            float4 xv = ((const float4*)xr)[f];
            uint2 pk;
            pk.x = (unsigned)f2bf(xv.x) | ((unsigned)f2bf(xv.y) << 16);
            pk.y = (unsigned)f2bf(xv.z) | ((unsigned)f2bf(xv.w) << 16);
            ((uint2*)(Xg + (size_t)s0 * DMODEL))[f] = pk;
            ((uint2*)(Xg + (size_t)s1 * DMODEL))[f] = pk;
        }
    }
}

// ---------------------------------------------------------------------------
// 2) grouped expert GEMM (v3 proven structure, BK=32):
//    C = A[M,K] * B + bias, bf16 out; B k-chunked [K/32][N][32].
//    FUSET (gemm1): 1-D grid of 2176 blocks, every 17 = 9 gemm + 8 W2T
//    transpose blocks -> co-resident, transpose rides gemm's idle BW.
template <int K, int N, bool RELU, bool FUSET>
__global__ __launch_bounds__(256) void expert_gemm(
    const ushort_t* __restrict__ A,
    const ushort_t* __restrict__ Bt,
    const float* __restrict__ bias,
    ushort_t* __restrict__ Cout,
    const int* __restrict__ gcnt,
    const float* __restrict__ Wsrc,    // W2 (FUSET only)
    ushort_t* __restrict__ Wdst)       // W2T (FUSET only)
{
    __shared__ __align__(16) ushort_t smem[FUSET ? 32 * 516 : 8192];
    const int tid = threadIdx.x;
    int e, nt, mt;
    if (FUSET) {
        const int bid = blockIdx.x;
        const int grp = bid / 17, rem = bid % 17;
        if (rem >= 9) {
            // W2: K=2048 -> 64 kc; N=1024 -> 2 strips; 128 blocks/expert
            int ti = grp * 8 + (rem - 9);         // [0,1024)
            int te = ti >> 7, idx = ti & 127;
            wt_block512(Wsrc + (size_t)te * DMODEL * FFN,
                        Wdst + (size_t)te * DMODEL * FFN,
                        DMODEL, idx >> 1, (idx & 1) * 512, smem, tid);
            return;
        }
        int gi = grp * 9 + rem;                   // [0,1152)
        e = gi & 7; nt = (gi >> 3) & 15; mt = gi >> 7;
    } else {
        e = blockIdx.x; nt = blockIdx.y; mt = blockIdx.z;
    }
    const int off_e = e * ECAP;
    if (mt * 128 >= gcnt[e * CNT_STRIDE]) return;

    ushort_t* As = smem;            // 128*32
    ushort_t* Bs = smem + 4096;     // 128*32

    const int lane = tid & 63;
    const int w    = tid >> 6;
    const int quad = lane >> 4;
    const int r16  = lane & 15;
    const int lrow = lane >> 2;                          // staging row 0..15
    const int lk   = (((lane & 3) ^ ((lane >> 3) & 3))) * 8;  // swizzled src k

    const size_t arow0 = (size_t)(off_e + mt * 128);
    const ushort_t* aS0 = A + (arow0 + (size_t)(2 * w + 0) * 16 + lrow) * K + lk;
    const ushort_t* aS1 = A + (arow0 + (size_t)(2 * w + 1) * 16 + lrow) * K + lk;
    const ushort_t* Bte = Bt + (size_t)e * N * K;
    // k-chunked B: element (kc, n, ks) at kc*N*32 + n*32 + ks; kc*N*32 == k0*N
    const ushort_t* bS0 = Bte + (size_t)(nt * 128 + (2 * w + 0) * 16 + lrow) * 32 + lk;
    const ushort_t* bS1 = Bte + (size_t)(nt * 128 + (2 * w + 1) * 16 + lrow) * 32 + lk;
    ushort_t* aD0 = &As[(2 * w + 0) * 512];
    ushort_t* aD1 = &As[(2 * w + 1) * 512];
    ushort_t* bD0 = &Bs[(2 * w + 0) * 512];
    ushort_t* bD1 = &Bs[(2 * w + 1) * 512];

    const int wm = (w >> 1) * 64;
    const int wn = (w & 1) * 64;
    const int sw = ((r16 >> 1) & 3) ^ quad;   // swizzled read chunk

    f32x4 acc[4][4];
    #pragma unroll
    for (int i = 0; i < 4; i++)
        #pragma unroll
        for (int j = 0; j < 4; j++)
            acc[i][j] = (f32x4){0.f, 0.f, 0.f, 0.f};

    for (int k0 = 0; k0 < K; k0 += 32) {
        gload_lds16(aS0 + k0, aD0);
        gload_lds16(aS1 + k0, aD1);
        gload_lds16(bS0 + (size_t)k0 * N, bD0);
        gload_lds16(bS1 + (size_t)k0 * N, bD1);
        __syncthreads();
        short8 af[4], bfr[4];
        #pragma unroll
        for (int i = 0; i < 4; i++)
            af[i] = *(const short8*)&As[(wm + i * 16 + r16) * 32 + sw * 8];
        #pragma unroll
        for (int j = 0; j < 4; j++)
            bfr[j] = *(const short8*)&Bs[(wn + j * 16 + r16) * 32 + sw * 8];
        #pragma unroll
        for (int i = 0; i < 4; i++)
            #pragma unroll
            for (int j = 0; j < 4; j++)
                acc[i][j] = __builtin_amdgcn_mfma_f32_16x16x32_bf16(
                    af[i], bfr[j], acc[i][j], 0, 0, 0);
        __syncthreads();
    }

    const float* be = bias + (size_t)e * N;
    #pragma unroll
    for (int i = 0; i < 4; i++) {
        #pragma unroll
        for (int j = 0; j < 4; j++) {
            int n = nt * 128 + wn + j * 16 + r16;
            float bv = be[n];
            #pragma unroll
            for (int r = 0; r < 4; r++) {
                int m = mt * 128 + wm + i * 16 + quad * 4 + r;
                float v = acc[i][j][r] + bv;
                if (RELU) v = v > 0.f ? v : 0.f;
                Cout[(size_t)(off_e + m) * N + n] = f2bf(v);
            }
        }
    }
}

// ---------------------------------------------------------------------------
// 3) fused mix + residual + LayerNorm
__global__ __launch_bounds__(256) void ln_kernel(
    const float* __restrict__ x, const ushort_t* __restrict__ O,
    const int* __restrict__ slot_of, const float* __restrict__ top_w,
    const float* __restrict__ gamma, const float* __restrict__ beta,
    float* __restrict__ out)
{
    int t = blockIdx.x, tid = threadIdx.x;
    int s0 = slot_of[2 * t], s1 = slot_of[2 * t + 1];
    float w0 = top_w[2 * t], w1 = top_w[2 * t + 1];
    float4 xv = ((const float4*)(x + (size_t)t * DMODEL))[tid];
    uint2 a = ((const uint2*)(O + (size_t)s0 * DMODEL))[tid];
    uint2 b = ((const uint2*)(O + (size_t)s1 * DMODEL))[tid];

    float y[4];
    y[0] = xv.x + w0 * bflo(a.x) + w1 * bflo(b.x);
    y[1] = xv.y + w0 * bfhi(a.x) + w1 * bfhi(b.x);
    y[2] = xv.z + w0 * bflo(a.y) + w1 * bflo(b.y);
    y[3] = xv.w + w0 * bfhi(a.y) + w1 * bfhi(b.y);

    float s = y[0] + y[1] + y[2] + y[3];
    float sq = y[0]*y[0] + y[1]*y[1] + y[2]*y[2] + y[3]*y[3];
    __shared__ float red[2][4];
    #pragma unroll
    for (int off = 32; off > 0; off >>= 1) {
        s += __shfl_down(s, off);
        sq += __shfl_down(sq, off);
    }
    int lane = tid & 63, wv = tid >> 6;
    if (lane == 0) { red[0][wv] = s; red[1][wv] = sq; }
    __syncthreads();
    if (tid == 0) {
        float S = red[0][0] + red[0][1] + red[0][2] + red[0][3];
        float SQ = red[1][0] + red[1][1] + red[1][2] + red[1][3];
        float mu = S * (1.f / DMODEL);
        float var = SQ * (1.f / DMODEL) - mu * mu;
        red[0][0] = mu;
        red[1][0] = rsqrtf(var + 1e-5f);
    }
    __syncthreads();
    float mu = red[0][0], inv = red[1][0];
    float4 gv = ((const float4*)gamma)[tid];
    float4 bv = ((const float4*)beta)[tid];
    float4 ov;
    ov.x = gv.x * (y[0] - mu) * inv + bv.x;
    ov.y = gv.y * (y[1] - mu) * inv + bv.y;
    ov.z = gv.z * (y[2] - mu) * inv + bv.z;
    ov.w = gv.w * (y[3] - mu) * inv + bv.w;
    ((float4*)(out + (size_t)t * DMODEL))[tid] = ov;
}

// ---------------------------------------------------------------------------
extern "C" void kernel_launch(void* const* d_in, const int* in_sizes, int n_in,
                              void* d_out, int out_size, void* d_ws, size_t ws_size,
                              hipStream_t stream)
{
    const float* x     = (const float*)d_in[0];
    const float* Wg    = (const float*)d_in[1];
    const float* bg    = (const float*)d_in[2];
    const float* W1    = (const float*)d_in[3];
    const float* b1    = (const float*)d_in[4];
    const float* W2    = (const float*)d_in[5];
    const float* b2    = (const float*)d_in[6];
    const float* gamma = (const float*)d_in[7];
    const float* beta  = (const float*)d_in[8];
    float* out = (float*)d_out;

    char* ws = (char*)d_ws;
    size_t o = 0;
    auto alloc = [&](size_t bytes) {
        size_t r = o;
        o = (o + bytes + 255) & ~(size_t)255;
        return r;
    };
    size_t o_cnt     = alloc(NEXP * CNT_STRIDE * 4);
    size_t o_topw    = alloc((size_t)T_TOKENS * 2 * 4);
    size_t o_slotof  = alloc((size_t)T_TOKENS * 2 * 4);
    size_t o_w1t     = alloc((size_t)NEXP * DMODEL * FFN * 2);
    size_t o_w2t     = alloc((size_t)NEXP * DMODEL * FFN * 2);
    size_t o_xg      = alloc((size_t)MAXSLOTS * DMODEL * 2);
    size_t o_h       = alloc((size_t)MAXSLOTS * FFN * 2);
    size_t o_obuf    = alloc((size_t)MAXSLOTS * DMODEL * 2);
    (void)ws_size; (void)in_sizes; (void)n_in; (void)out_size;

    int*      gcnt     = (int*)(ws + o_cnt);
    float*    top_w    = (float*)(ws + o_topw);
    int*      slot_of  = (int*)(ws + o_slotof);
    ushort_t* W1T      = (ushort_t*)(ws + o_w1t);
    ushort_t* W2T      = (ushort_t*)(ws + o_w2t);
    ushort_t* Xg       = (ushort_t*)(ws + o_xg);
    ushort_t* H        = (ushort_t*)(ws + o_h);
    ushort_t* Obuf     = (ushort_t*)(ws + o_obuf);

    hipMemsetAsync(gcnt, 0, NEXP * CNT_STRIDE * sizeof(int), stream);
    prep_kernel<<<GATE_BLKS + 1024, 256, 0, stream>>>(
        W1, W1T, x, Wg, bg, gcnt, slot_of, top_w, Xg);
    expert_gemm<DMODEL, FFN, true, true>
        <<<2176, 256, 0, stream>>>(Xg, W1T, b1, H, gcnt, W2, W2T);
    expert_gemm<FFN, DMODEL, false, false>
        <<<dim3(NEXP, DMODEL / 128, MT1), 256, 0, stream>>>(
            H, W2T, b2, Obuf, gcnt, nullptr, nullptr);
    ln_kernel<<<T_TOKENS, 256, 0, stream>>>(x, Obuf, slot_of, top_w, gamma, beta, out);
}